// Round 9
// baseline (243.983 us; speedup 1.0000x reference)
//
#include <hip/hip_runtime.h>
#include <hip/hip_bf16.h>

#define BB 8
#define NN 16384
#define DD 1024
#define AA 128

typedef __attribute__((ext_vector_type(8))) short bf16x8;
typedef __attribute__((ext_vector_type(4))) float f32x4;
typedef __attribute__((ext_vector_type(4))) unsigned short u16x4;

__device__ __forceinline__ unsigned short f2bf(float x) {
  union { __hip_bfloat16 h; unsigned short u; } cv;
  cv.h = __float2bfloat16(x);
  return cv.u;
}

__device__ __forceinline__ float softplusf(float x) {
  return fmaxf(x, 0.f) + log1pf(expf(-fabsf(x)));
}

// order-preserving float->uint map (monotone)
__device__ __forceinline__ unsigned int ordu(float x) {
  unsigned int u = __float_as_uint(x);
  return (u & 0x80000000u) ? ~u : (u | 0x80000000u);
}

// LDS index swizzle for k_select
__device__ __forceinline__ int fvx(int i) {
  return i ^ ((i >> 6) & 63);
}

// ---------------------------------------------------------------------------
// Kernel 0: W1 -> W1T (bf16, [A=128][D=1024]); zero out[8..9].
// ---------------------------------------------------------------------------
__global__ __launch_bounds__(256) void k_prep(
    const float* __restrict__ W1, unsigned short* __restrict__ W1T,
    float* __restrict__ out) {
  const int gid = blockIdx.x * 256 + threadIdx.x;
  if (gid == 0) { out[8] = 0.f; out[9] = 0.f; }
  if (gid < DD * AA) {
    const int col = gid >> 10;
    const int k   = gid & 1023;
    W1T[gid] = f2bf(W1[k * AA + col]);
  }
}

// ---------------------------------------------------------------------------
// Kernel 1: f[n] = b2 + sum_a w2[a] tanh((X W1)[n][a] + b1[a]);
//           y[n] = X[n,:] . Wc  (same staged registers).
// R8 structure + T14 async-STAGE split: issue loads(st+1) right after the
// post-write barrier so HBM latency hides under the MFMA phase of step st.
// ---------------------------------------------------------------------------
__global__ __launch_bounds__(256, 3) void k_scores(
    const float* __restrict__ X, const unsigned short* __restrict__ W1T,
    const float* __restrict__ b1, const float* __restrict__ w2,
    const float* __restrict__ b2p, const float* __restrict__ Wc,
    float* __restrict__ f, float* __restrict__ y) {
  __shared__ unsigned short As[128 * 64];   // [row][k] bf16, swizzled
  __shared__ unsigned short Bs[128 * 64];   // [col][k] bf16, swizzled
  __shared__ float fpart[128];
  const int t = threadIdx.x;
  const int lane = t & 63;
  const int wv = t >> 6;
  const int wr = wv >> 1, wc = wv & 1;
  const int l15 = lane & 15, lg = lane >> 4;
  const size_t row0 = (size_t)blockIdx.x * 128;
  const float* Xb = X + row0 * DD;

  f32x4 zero4 = {0.f, 0.f, 0.f, 0.f};
  f32x4 acc[4][4];
#pragma unroll
  for (int mi = 0; mi < 4; ++mi)
#pragma unroll
    for (int ni = 0; ni < 4; ++ni) acc[mi][ni] = zero4;

  float yp[8];
#pragma unroll
  for (int j = 0; j < 8; ++j) yp[j] = 0.f;

  const int kq = (t & 15) * 4;              // this thread's k-offset
  const int rbase = t >> 4;                 // row group base
  const int bcol = t >> 3, bch = t & 7;     // B staging coords

  float4 st[8];                             // staged A (f32)
  bf16x8 sb[4];                             // staged B
  float4 wc4;

  // ---- prologue: issue loads for step 0 ----
  {
    const int k0 = 0;
#pragma unroll
    for (int j = 0; j < 8; ++j)
      st[j] = *(const float4*)(Xb + (size_t)(rbase + j * 16) * DD + k0 + kq);
#pragma unroll
    for (int j = 0; j < 4; ++j)
      sb[j] = *(const bf16x8*)(W1T + (size_t)(bcol + j * 32) * DD + k0 + bch * 8);
    wc4 = *(const float4*)(Wc + k0 + kq);
  }

  for (int stp = 0; stp < 16; ++stp) {
    // ---- write phase: consume staged regs (compiler inserts vmcnt waits) ----
#pragma unroll
    for (int j = 0; j < 8; ++j) {
      const int r = rbase + j * 16;
      yp[j] += st[j].x * wc4.x + st[j].y * wc4.y + st[j].z * wc4.z + st[j].w * wc4.w;
      u16x4 p;
      p.x = f2bf(st[j].x); p.y = f2bf(st[j].y);
      p.z = f2bf(st[j].z); p.w = f2bf(st[j].w);
      const int idx = r * 64 + (((kq >> 3) ^ (r & 7)) << 3) + (kq & 7);
      *(u16x4*)&As[idx] = p;
    }
#pragma unroll
    for (int j = 0; j < 4; ++j) {
      const int col = bcol + j * 32;
      *(bf16x8*)&Bs[col * 64 + ((bch ^ (col & 7)) << 3)] = sb[j];
    }
    __syncthreads();

    // ---- issue next step's loads (in flight under the MFMA phase) ----
    if (stp < 15) {
      const int k0 = (stp + 1) * 64;
#pragma unroll
      for (int j = 0; j < 8; ++j)
        st[j] = *(const float4*)(Xb + (size_t)(rbase + j * 16) * DD + k0 + kq);
#pragma unroll
      for (int j = 0; j < 4; ++j)
        sb[j] = *(const bf16x8*)(W1T + (size_t)(bcol + j * 32) * DD + k0 + bch * 8);
      wc4 = *(const float4*)(Wc + k0 + kq);
    }

    // ---- MFMA over LDS tile ----
#pragma unroll
    for (int ks = 0; ks < 2; ++ks) {
      bf16x8 af[4], bg[4];
      const int chunk = ks * 4 + lg;
#pragma unroll
      for (int mi = 0; mi < 4; ++mi) {
        const int r = wr * 64 + mi * 16 + l15;
        af[mi] = *(const bf16x8*)&As[r * 64 + ((chunk ^ (r & 7)) << 3)];
      }
#pragma unroll
      for (int ni = 0; ni < 4; ++ni) {
        const int c = wc * 64 + ni * 16 + l15;
        bg[ni] = *(const bf16x8*)&Bs[c * 64 + ((chunk ^ (c & 7)) << 3)];
      }
#pragma unroll
      for (int mi = 0; mi < 4; ++mi)
#pragma unroll
        for (int ni = 0; ni < 4; ++ni)
          acc[mi][ni] = __builtin_amdgcn_mfma_f32_16x16x32_bf16(
              af[mi], bg[ni], acc[mi][ni], 0, 0, 0);
    }
    __syncthreads();
  }

  // y: reduce yp[j] across the 16 lanes sharing each row
#pragma unroll
  for (int j = 0; j < 8; ++j) {
    float s = yp[j];
    s += __shfl_xor(s, 1);
    s += __shfl_xor(s, 2);
    s += __shfl_xor(s, 4);
    s += __shfl_xor(s, 8);
    if ((t & 15) == 0) y[row0 + rbase + j * 16] = s;
  }

  // f epilogue (R1-verified)
  const float b2 = b2p[0];
  float w2c[4], b1c[4];
#pragma unroll
  for (int ni = 0; ni < 4; ++ni) {
    const int c = wc * 64 + ni * 16 + l15;
    w2c[ni] = w2[c];
    b1c[ni] = b1[c];
  }
  float pr[4][4];
#pragma unroll
  for (int mi = 0; mi < 4; ++mi) {
#pragma unroll
    for (int q = 0; q < 4; ++q) {
      float s = 0.f;
#pragma unroll
      for (int ni = 0; ni < 4; ++ni)
        s += w2c[ni] * tanhf(acc[mi][ni][q] + b1c[ni]);
      s += __shfl_xor(s, 1);
      s += __shfl_xor(s, 2);
      s += __shfl_xor(s, 4);
      s += __shfl_xor(s, 8);
      pr[mi][q] = s;
    }
  }
  if (wc == 1 && l15 == 0) {
#pragma unroll
    for (int mi = 0; mi < 4; ++mi)
#pragma unroll
      for (int q = 0; q < 4; ++q)
        fpart[wr * 64 + mi * 16 + lg * 4 + q] = pr[mi][q];
  }
  __syncthreads();
  if (wc == 0 && l15 == 0) {
#pragma unroll
    for (int mi = 0; mi < 4; ++mi)
#pragma unroll
      for (int q = 0; q < 4; ++q) {
        const int rl = wr * 64 + mi * 16 + lg * 4 + q;
        f[row0 + rl] = pr[mi][q] + fpart[rl] + b2;
      }
  }
}

// ---------------------------------------------------------------------------
// Kernel 2: per bag (1 block, 1024 thr):
//  (a) masked m, Z, Sy -> bag_pred, crit_loss
//  (b) top/bottom-64 ids via 4-pass byte radix select (ties: lowest index)
// ---------------------------------------------------------------------------
__global__ __launch_bounds__(1024) void k_select(
    const float* __restrict__ f, const float* __restrict__ y,
    const float* __restrict__ mask, const int* __restrict__ labels,
    const float* __restrict__ bc, int* __restrict__ sel,
    float* __restrict__ out) {
  __shared__ unsigned int uv[NN];     // 64 KB, swizzled via fvx()
  __shared__ unsigned int hist[256];
  __shared__ unsigned int wq[16];
  __shared__ unsigned int sb[4];
  __shared__ float redf[16];
  const int t = threadIdx.x;
  const int lane = t & 63, w = t >> 6;
  const int b = blockIdx.x;
  const float* fb = f + (size_t)b * NN;
  const float* yb = y + (size_t)b * NN;
  const float* kb = mask + (size_t)b * NN;

  // load keys + masked max
  float mx = -3.0e38f;
  for (int i = t; i < NN; i += 1024) {
    const float v = fb[i];
    uv[fvx(i)] = ordu(v);
    mx = fmaxf(mx, kb[i] > 0.f ? v : -1.0e30f);
  }
#pragma unroll
  for (int s = 1; s < 64; s <<= 1) mx = fmaxf(mx, __shfl_xor(mx, s));
  if (lane == 0) redf[w] = mx;
  __syncthreads();
  float m = redf[0];
#pragma unroll
  for (int q = 1; q < 16; ++q) m = fmaxf(m, redf[q]);
  __syncthreads();

  // Z and Sy
  float se = 0.f, sy = 0.f;
  for (int i = t; i < NN; i += 1024) {
    if (kb[i] > 0.f) {
      const float e = expf(fb[i] - m);
      se += e;
      sy += e * yb[i];
    }
  }
#pragma unroll
  for (int s = 1; s < 64; s <<= 1) se += __shfl_xor(se, s);
  if (lane == 0) redf[w] = se;
  __syncthreads();
  float Z = 0.f;
#pragma unroll
  for (int q = 0; q < 16; ++q) Z += redf[q];
  __syncthreads();
#pragma unroll
  for (int s = 1; s < 64; s <<= 1) sy += __shfl_xor(sy, s);
  if (lane == 0) redf[w] = sy;
  __syncthreads();
  if (t == 0) {
    float Sy = 0.f;
#pragma unroll
    for (int q = 0; q < 16; ++q) Sy += redf[q];
    const float bp = Sy / Z + bc[0];
    out[b] = bp;
    const float lf = (float)labels[b];
    atomicAdd(out + 8, (softplusf(bp) - bp * lf) * 0.125f);
  }
  __syncthreads();

  // radix select (R7-verified)
  const int i0 = t * 16;
  for (int mode = 0; mode < 2; ++mode) {
    unsigned int pref = 0u, above = 0u, krem = 64u;
    for (int p = 3; p >= 0; --p) {
      if (t < 256) hist[t] = 0u;
      __syncthreads();
      const unsigned int pmask = (p == 3) ? 0u : (0xFFFFFFFFu << ((p + 1) * 8));
      for (int j = 0; j < 16; ++j) {
        unsigned int u = uv[fvx(i0 + j)];
        if (mode) u = ~u;
        if ((u & pmask) == pref)
          atomicAdd(&hist[(u >> (p * 8)) & 255u], 1u);
      }
      __syncthreads();
      unsigned int v = 0, s = 0;
      if (t < 256) {
        v = hist[t];
        s = v;
#pragma unroll
        for (int off = 1; off < 64; off <<= 1) {
          const unsigned int o = __shfl_down(s, off);
          if (lane + off < 64) s += o;
        }
        if (lane == 0) wq[w] = s;
      }
      __syncthreads();
      if (t < 256) {
        unsigned int hi = 0;
        for (int q = w + 1; q < 4; ++q) hi += wq[q];
        const unsigned int Ssuf = s + hi;
        const unsigned int Snext = Ssuf - v;
        if (Ssuf >= krem && Snext < krem) {
          sb[0] = pref | ((unsigned int)t << (p * 8));
          sb[1] = above + Snext;
          sb[2] = krem - Snext;
          sb[3] = 0u;
        }
      }
      __syncthreads();
      pref = sb[0]; above = sb[1]; krem = sb[2];
    }
    const int off = b * 128 + mode * 64;
    unsigned int myt = 0;
    for (int j = 0; j < 16; ++j) {
      unsigned int u = uv[fvx(i0 + j)];
      if (mode) u = ~u;
      if (u > pref) {
        const unsigned int pos = atomicAdd(&sb[3], 1u);
        sel[off + pos] = i0 + j;
      } else if (u == pref) {
        myt++;
      }
    }
    unsigned int pv = myt;
#pragma unroll
    for (int o2 = 1; o2 < 64; o2 <<= 1) {
      const unsigned int o = __shfl_up(pv, o2);
      if (lane >= o2) pv += o;
    }
    __syncthreads();
    if (lane == 63) wq[w] = pv;
    __syncthreads();
    unsigned int base = 0;
    for (int q = 0; q < w; ++q) base += wq[q];
    unsigned int gg = base + pv - myt;
    for (int j = 0; j < 16 && myt > 0; ++j) {
      unsigned int u = uv[fvx(i0 + j)];
      if (mode) u = ~u;
      if (u == pref) {
        if (gg < krem) sel[off + above + gg] = i0 + j;
        gg++;
        myt--;
      }
    }
    __syncthreads();
  }
}

// ---------------------------------------------------------------------------
// Kernel 3: instance smooth-top1-SVM losses (bag terms done in k_select).
// grid = 32 (bag = blk>>2, row-quarter = blk&3).
// ---------------------------------------------------------------------------
__global__ __launch_bounds__(256) void k_final(
    const float* __restrict__ X, const int* __restrict__ labels,
    const int* __restrict__ sel, const float* __restrict__ Wi,
    const float* __restrict__ bi, float* __restrict__ out) {
  const int b = blockIdx.x >> 2, part = blockIdx.x & 3;
  const int t = threadIdx.x;
  const int lane = t & 63, w = t >> 6;
  __shared__ float sin_[4], sout_[4];
  const int label = labels[b];

  const float* Win = Wi + label * (DD * 2);
  const float* Wot = Wi + (1 - label) * (DD * 2);
  const float bin0 = bi[label * 2], bin1 = bi[label * 2 + 1];
  const float bo0 = bi[(1 - label) * 2], bo1 = bi[(1 - label) * 2 + 1];
  float ain = 0.f, aout = 0.f;
  for (int ii = 0; ii < 8; ++ii) {
    const int r = part * 32 + w * 8 + ii;     // 0..127
    const int id = sel[b * 128 + r];
    const float* xr = X + ((size_t)b * NN + id) * DD;
    float p0 = 0.f, p1 = 0.f, p2 = 0.f, p3 = 0.f;
#pragma unroll
    for (int j = 0; j < 16; j += 4) {
      const int d = lane * 16 + j;
      const float4 x = *(const float4*)(xr + d);
      const float4 wa = *(const float4*)(Win + d * 2);
      const float4 wb = *(const float4*)(Win + d * 2 + 4);
      p0 += x.x * wa.x + x.y * wa.z + x.z * wb.x + x.w * wb.z;
      p1 += x.x * wa.y + x.y * wa.w + x.z * wb.y + x.w * wb.w;
      if (r < 64) {
        const float4 oa = *(const float4*)(Wot + d * 2);
        const float4 ob = *(const float4*)(Wot + d * 2 + 4);
        p2 += x.x * oa.x + x.y * oa.z + x.z * ob.x + x.w * ob.z;
        p3 += x.x * oa.y + x.y * oa.w + x.z * ob.y + x.w * ob.w;
      }
    }
#pragma unroll
    for (int sh = 1; sh < 64; sh <<= 1) {
      p0 += __shfl_xor(p0, sh);
      p1 += __shfl_xor(p1, sh);
      p2 += __shfl_xor(p2, sh);
      p3 += __shfl_xor(p3, sh);
    }
    if (lane == 0) {
      const float l0 = p0 + bin0, l1 = p1 + bin1;
      ain += (r < 64) ? softplusf(l0 + 1.f - l1) : softplusf(l1 + 1.f - l0);
      if (r < 64) aout += softplusf((p3 + bo1) + 1.f - (p2 + bo0));
    }
  }
  if (lane == 0) { sin_[w] = ain; sout_[w] = aout; }
  __syncthreads();
  if (t == 0) {
    const float ti = sin_[0] + sin_[1] + sin_[2] + sin_[3];
    const float to = sout_[0] + sout_[1] + sout_[2] + sout_[3];
    atomicAdd(out + 9, ti * (1.0f / 128.0f) + to * (1.0f / 64.0f));
  }
}

// ---------------------------------------------------------------------------

extern "C" void kernel_launch(void* const* d_in, const int* in_sizes, int n_in,
                              void* d_out, int out_size, void* d_ws, size_t ws_size,
                              hipStream_t stream) {
  const float* X      = (const float*)d_in[0];
  const float* mask   = (const float*)d_in[1];
  const int*   labels = (const int*)d_in[2];
  const float* W1     = (const float*)d_in[3];
  const float* b1     = (const float*)d_in[4];
  const float* w2     = (const float*)d_in[5];
  const float* b2     = (const float*)d_in[6];
  const float* Wc     = (const float*)d_in[7];
  const float* bc     = (const float*)d_in[8];
  const float* Wi     = (const float*)d_in[9];
  const float* bi     = (const float*)d_in[10];
  float* out = (float*)d_out;

  float* ws  = (float*)d_ws;
  float* f   = ws;                             // 131072 f32
  float* y   = ws + 131072;                    // 131072 f32
  int*   sel = (int*)(ws + 262144);            // 1024 int
  unsigned short* W1T = (unsigned short*)(ws + 263168);  // 131072 bf16

  k_prep  <<<512,  256, 0, stream>>>(W1, W1T, out);
  k_scores<<<1024, 256, 0, stream>>>(X, W1T, b1, w2, b2, Wc, f, y);
  k_select<<<8,   1024, 0, stream>>>(f, y, mask, labels, bc, sel, out);
  k_final <<<32,   256, 0, stream>>>(X, labels, sel, Wi, bi, out);
}